// Round 9
// baseline (1182.086 us; speedup 1.0000x reference)
//
#include <hip/hip_runtime.h>

// HMM forward, B=64, T=1024, S=512, V=1024.
// One block per batch. E = exp(trans) quantized u8 (per-row scale folded into
// P's quantization). K=512 reduction split across BOTH pipes (m114 co-issue):
//   kap 0..3 (i in [0,256)):  v_mfma_i32_16x16x64_i8, B-frags in regs,
//                             all 16 A-rows identical (quad-broadcast P reads)
//   kap 4..7 (i in [256,512)): v_sdot4 in VALU, E dwords in regs,
//                             broadcast P dword reads
// Both partials are exact i32 at the same scale -> single integer add.
// r7's 2-barrier exact-max structure retained (r8's 1-barrier combine regressed).

constexpr int Bn = 64, Tn = 1024, Sn = 512;
#define L2E 1.44269504f

typedef int v4i __attribute__((ext_vector_type(4)));

__device__ __forceinline__ int dot4(int e, int p, int acc) {
#if __has_builtin(__builtin_amdgcn_sdot4)
    return __builtin_amdgcn_sdot4(e, p, acc, false);
#else
    acc += (int)(signed char)(e) * (int)(signed char)(p);
    acc += (int)(signed char)(e >> 8) * (int)(signed char)(p >> 8);
    acc += (int)(signed char)(e >> 16) * (int)(signed char)(p >> 16);
    acc += (int)(signed char)(e >> 24) * (int)(signed char)(p >> 24);
    return acc;
#endif
}

#if __has_builtin(__builtin_amdgcn_update_dpp)
template <int CTRL>
__device__ __forceinline__ float dpp_fmax(float x) {
    int s = __builtin_bit_cast(int, x);
    int d = __builtin_amdgcn_update_dpp(s, s, CTRL, 0xf, 0xf, false);
    return fmaxf(x, __builtin_bit_cast(float, d));
}
__device__ __forceinline__ float wave_max64(float x) {
    x = dpp_fmax<0x121>(x);   // row_ror:1
    x = dpp_fmax<0x122>(x);   // row_ror:2
    x = dpp_fmax<0x124>(x);   // row_ror:4
    x = dpp_fmax<0x128>(x);   // row_ror:8
    x = dpp_fmax<0x142>(x);   // row_bcast:15
    x = dpp_fmax<0x143>(x);   // row_bcast:31
    return __builtin_bit_cast(float,
        __builtin_amdgcn_readlane(__builtin_bit_cast(int, x), 63));
}
// Max over period-8 lane pattern (lane holds v[lane&7]) -> all lanes get max.
__device__ __forceinline__ float max_of_8_pattern(float x) {
    x = dpp_fmax<0x121>(x);
    x = dpp_fmax<0x122>(x);
    x = dpp_fmax<0x124>(x);
    return x;
}
#else
__device__ __forceinline__ float wave_max64(float x) {
    #pragma unroll
    for (int off = 32; off; off >>= 1) x = fmaxf(x, __shfl_xor(x, off, 64));
    return x;
}
__device__ __forceinline__ float max_of_8_pattern(float x) {
    #pragma unroll
    for (int off = 1; off < 8; off <<= 1) x = fmaxf(x, __shfl_xor(x, off, 64));
    return x;
}
#endif

// Eq value for (row i, col c) -> B-fragment byte address:
// frag = (c>>4)*8 + (i>>6); lane = ((i>>4)&3)*16 + (c&15); byte = i&15
__device__ __forceinline__ int bfrag_addr(int i, int c) {
    return ((((c >> 4) * 8 + (i >> 6)) * 64) + ((i >> 4) & 3) * 16 + (c & 15)) * 16
           + (i & 15);
}

// One block per row i: rowmax + quantize row to u8; write BOTH layouts:
// B-frag layout (MFMA half) and dot4 layout uint E2u[(i>>2)*512 + j].
__global__ __launch_bounds__(256) void prep_rows(
    const float* __restrict__ trans, unsigned char* __restrict__ EqB,
    unsigned char* __restrict__ E2, float* __restrict__ rowmax)
{
    const int i = blockIdx.x;
    const int j = threadIdx.x;
    const int lane = j & 63, wv = j >> 6;
    float t0 = trans[i * Sn + j];
    float t1 = trans[i * Sn + j + 256];
    float m = fmaxf(t0, t1);
    #pragma unroll
    for (int off = 32; off; off >>= 1) m = fmaxf(m, __shfl_xor(m, off, 64));
    __shared__ float rm[4];
    if (lane == 0) rm[wv] = m;
    __syncthreads();
    m = fmaxf(fmaxf(rm[0], rm[1]), fmaxf(rm[2], rm[3]));
    if (j == 0) rowmax[i] = m;
    int q0 = __float2int_rn(127.f * __expf(t0 - m));
    int q1 = __float2int_rn(127.f * __expf(t1 - m));
    EqB[bfrag_addr(i, j)] = (unsigned char)q0;
    EqB[bfrag_addr(i, j + 256)] = (unsigned char)q1;
    E2[(i >> 2) * 2048 + j * 4 + (i & 3)] = (unsigned char)q0;
    E2[(i >> 2) * 2048 + (j + 256) * 4 + (i & 3)] = (unsigned char)q1;
}

// lr[i] = log2(127 * exp(rowmax_i - RM)); C = RM - 2*ln(127)
__global__ __launch_bounds__(512) void prep_scale(
    const float* __restrict__ rowmax, float* __restrict__ lr,
    float* __restrict__ Cp)
{
    const int i = threadIdx.x;
    const int lane = i & 63, wv = i >> 6;
    float m = rowmax[i];
    float rm = m;
    #pragma unroll
    for (int off = 32; off; off >>= 1) rm = fmaxf(rm, __shfl_xor(rm, off, 64));
    __shared__ float red[8];
    if (lane == 0) red[wv] = rm;
    __syncthreads();
    float RM = red[0];
    #pragma unroll
    for (int w = 1; w < 8; ++w) RM = fmaxf(RM, red[w]);
    lr[i] = (m - RM) * L2E + 6.98868469f;           // log2(127)
    if (i == 0) *Cp = RM - 9.68837417f;             // 2*ln(127)
}

__global__ __launch_bounds__(512, 2) void hmm_fwd(
    const int* __restrict__ obs,          // [B, T]
    const float* __restrict__ emis,       // [V, S]
    const float* __restrict__ prior,      // [S]
    const v4i* __restrict__ EqB4,         // B-fragments (MFMA half)
    const int* __restrict__ E2u,          // dot4 layout (VALU half)
    const float* __restrict__ lr,         // [S]
    const float* __restrict__ Cp,         // scalar
    float* __restrict__ out)              // [B]
{
    const int b = blockIdx.x;
    const int tid = threadIdx.x;          // state j owned by this thread
    const int lane = tid & 63, wv = tid >> 6;
    const int q = lane >> 4;

    __shared__ int obs_s[Tn];
    __shared__ __align__(16) unsigned char Pq[2][Sn];
    __shared__ float redm[2][8];
    __shared__ float reds[8];

    obs_s[tid] = obs[b * Tn + tid];
    obs_s[tid + 512] = obs[b * Tn + 512 + tid];

    // MFMA half: B-frags for kap 0..3 (i in [0,256))
    v4i Bf[4][4];
    #pragma unroll
    for (int tau = 0; tau < 4; ++tau)
        #pragma unroll
        for (int kap = 0; kap < 4; ++kap)
            Bf[tau][kap] = EqB4[((wv * 4 + tau) * 8 + kap) * 64 + lane];

    // VALU half: E dwords for i in [256,512): Ed[k] = rows 256+4k..+3, col tid
    int Ed[64];
    #pragma unroll
    for (int k = 0; k < 64; ++k) Ed[k] = E2u[(64 + k) * Sn + tid];

    const float lr_t = lr[tid];
    const float C = *Cp;

    __syncthreads();   // obs_s ready

    float a = emis[obs_s[0] * Sn + tid] + prior[tid];
    float e_next = emis[obs_s[1] * Sn + tid];

    for (int t = 1; t < Tn; ++t) {
        const int pb = t & 1;

        // ---- exact block max: DPP in-wave, one b32 LDS round-trip cross-wave
        float mw = wave_max64(a);
        if (lane == 0) redm[pb][wv] = mw;
        __syncthreads();                          // barrier 1
        float m = max_of_8_pattern(redm[pb][lane & 7]);

        // ---- quantize P (u8, row-scale folded) into linear byte vector
        int gi = __float2int_rn(exp2f(fmaf(a - m, L2E, lr_t)));
        Pq[pb][tid] = (unsigned char)gi;
        __syncthreads();                          // barrier 2

        float e_cur = e_next;
        if (t < Tn - 1) e_next = emis[obs_s[t + 1] * Sn + tid];

        // ---- MFMA half: A-frags quad-broadcast (all 16 A-rows identical)
        const unsigned char* Pbase = Pq[pb] + q * 16;
        v4i Af[4];
        #pragma unroll
        for (int kap = 0; kap < 4; ++kap)
            Af[kap] = *(const v4i*)(Pbase + kap * 64);

        v4i acc[4];
        #pragma unroll
        for (int tau = 0; tau < 4; ++tau) {
            v4i z = {0, 0, 0, 0};
            #pragma unroll
            for (int kap = 0; kap < 4; ++kap)
                z = __builtin_amdgcn_mfma_i32_16x16x64_i8(Af[kap], Bf[tau][kap],
                                                          z, 0, 0, 0);
            acc[tau] = z;
        }

        // ---- VALU half: dot4 over i in [256,512), broadcast P dword reads
        const v4i* Pd = (const v4i*)(Pq[pb] + 256);
        int ac0 = 0, ac1 = 0, ac2 = 0, ac3 = 0;
        #pragma unroll
        for (int c = 0; c < 16; ++c) {
            v4i p = Pd[c];                        // wave-uniform broadcast
            ac0 = dot4(Ed[4 * c + 0], p.x, ac0);
            ac1 = dot4(Ed[4 * c + 1], p.y, ac1);
            ac2 = dot4(Ed[4 * c + 2], p.z, ac2);
            ac3 = dot4(Ed[4 * c + 3], p.w, ac3);
        }
        int idsum = (ac0 + ac1) + (ac2 + ac3);

        // ---- every C row equals the result: select tau = lane>>4 in-register
        int im = (lane < 16) ? acc[0].x
               : (lane < 32) ? acc[1].x
               : (lane < 48) ? acc[2].x
                             : acc[3].x;

        a = e_cur + m + C + __logf((float)(im + idsum));
    }

    // ---- out[b] = logsumexp_j(alpha[j])
    float m = a;
    #pragma unroll
    for (int off = 32; off; off >>= 1) m = fmaxf(m, __shfl_xor(m, off, 64));
    if (lane == 0) redm[0][wv] = m;
    __syncthreads();
    #pragma unroll
    for (int w = 0; w < 8; ++w) m = fmaxf(m, redm[0][w]);

    float s = __expf(a - m);
    #pragma unroll
    for (int off = 32; off; off >>= 1) s += __shfl_xor(s, off, 64);
    if (lane == 0) reds[wv] = s;
    __syncthreads();
    if (tid == 0) {
        float tot = 0.f;
        #pragma unroll
        for (int w = 0; w < 8; ++w) tot += reds[w];
        out[b] = m + __logf(tot);
    }
}

extern "C" void kernel_launch(void* const* d_in, const int* in_sizes, int n_in,
                              void* d_out, int out_size, void* d_ws, size_t ws_size,
                              hipStream_t stream) {
    const int*   obs   = (const int*)d_in[0];
    const float* emis  = (const float*)d_in[1];
    const float* trans = (const float*)d_in[2];
    const float* prior = (const float*)d_in[3];
    float* out = (float*)d_out;

    unsigned char* EqB = (unsigned char*)d_ws;                // 256 KB
    unsigned char* E2  = EqB + Sn * Sn;                       // 256 KB
    float* rowmax = (float*)(E2 + Sn * Sn);                   // 2 KB
    float* lr     = rowmax + Sn;                              // 2 KB
    float* Cp     = lr + Sn;                                  // 4 B

    prep_rows<<<Sn, 256, 0, stream>>>(trans, EqB, E2, rowmax);
    prep_scale<<<1, Sn, 0, stream>>>(rowmax, lr, Cp);
    hmm_fwd<<<Bn, Sn, 0, stream>>>(obs, emis, prior,
                                   (const v4i*)EqB, (const int*)E2,
                                   lr, Cp, out);
}

// Round 11
// 1143.357 us; speedup vs baseline: 1.0339x; 1.0339x over previous
//
#include <hip/hip_runtime.h>

// HMM forward, B=64, T=1024, S=512, V=1024.
// One block per batch, thread j owns state j. E = exp(trans) quantized to
// FP6 e2m3 with per-(col,32-row-block) e8m0 scales (native MX). P = exp(a-m)
// quantized to fp6 with per-64-chunk e8m0 scales. Inner product:
// mfma_scale_f32_16x16x128_f8f6f4 (fp6 x fp6, K=128, f32 out), all 16 A-rows
// identical (quad-broadcast packed-P reads) -> every C row is the result.

constexpr int Bn = 64, Tn = 1024, Sn = 512;
#define L2E 1.44269504f

typedef int v8i __attribute__((ext_vector_type(8)));
typedef float v4f __attribute__((ext_vector_type(4)));

template <int CTRL>
__device__ __forceinline__ int dpp_i(int x) {
    return __builtin_amdgcn_update_dpp(x, x, CTRL, 0xf, 0xf, false);
}
template <int CTRL>
__device__ __forceinline__ float dpp_fmax(float x) {
    int s = __builtin_bit_cast(int, x);
    int d = dpp_i<CTRL>(s);
    return fmaxf(x, __builtin_bit_cast(float, d));
}
__device__ __forceinline__ float wave_max64(float x) {
    x = dpp_fmax<0x121>(x);   // row_ror:1
    x = dpp_fmax<0x122>(x);   // row_ror:2
    x = dpp_fmax<0x124>(x);   // row_ror:4
    x = dpp_fmax<0x128>(x);   // row_ror:8
    x = dpp_fmax<0x142>(x);   // row_bcast:15
    x = dpp_fmax<0x143>(x);   // row_bcast:31
    return __builtin_bit_cast(float,
        __builtin_amdgcn_readlane(__builtin_bit_cast(int, x), 63));
}
__device__ __forceinline__ float max_of_8_pattern(float x) {
    x = dpp_fmax<0x121>(x);
    x = dpp_fmax<0x122>(x);
    x = dpp_fmax<0x124>(x);
    return x;
}
__device__ __forceinline__ int rl_i(int x, int l) {
    return __builtin_amdgcn_readlane(x, l);
}

// round-to-nearest e2m3 code (0..31, sign 0) for v in [0, 7.5].
// grids: [0,2): k/8; [2,4): k/4; [4,7.5]: k/2. Continuous at boundaries.
__device__ __forceinline__ int e2m3_rn(float v) {
    v = fminf(v, 7.5f);
    float mult = v < 2.f ? 8.f : (v < 4.f ? 4.f : 2.f);
    int   add  = v < 2.f ? 0   : (v < 4.f ? 8   : 16);
    return (int)rintf(v * mult) + add;
}

// ---- prep: quantize E to fp6 e2m3, dense 6-bit packed in MFMA-B lane fields.
// grid 128 x 64: thread handles (col j = 4*bx + t>>4, 32-row block rb = t&15)
// = exactly one 192-bit lane field.
__global__ __launch_bounds__(64) void prep_E6(
    const float* __restrict__ trans, unsigned int* __restrict__ EqB6,
    unsigned char* __restrict__ SBtab)
{
    const int t = threadIdx.x;
    const int j = blockIdx.x * 4 + (t >> 4);
    const int rb = t & 15;

    float tv[32]; float tmax = -1e30f;
    #pragma unroll
    for (int k = 0; k < 32; ++k) {
        tv[k] = trans[(rb * 32 + k) * Sn + j];
        tmax = fmaxf(tmax, tv[k]);
    }
    // scale e: max value maps into (3.75, 7.5]
    float e = ceilf(fmaf(tmax, L2E, -2.9068906f));   // log2(7.5)

    unsigned dw[6] = {0, 0, 0, 0, 0, 0};
    #pragma unroll
    for (int k = 0; k < 32; ++k) {
        float v = exp2f(fmaf(tv[k], L2E, -e));
        unsigned c = (unsigned)e2m3_rn(v);
        int bit = 6 * k;
        dw[bit >> 5] |= c << (bit & 31);
        if ((bit & 31) > 26) dw[(bit >> 5) + 1] |= c >> (32 - (bit & 31));
    }

    // lane field address: frag = ((j>>6)*4 + ((j>>4)&3))*4 + (rb>>2);
    // lane = (rb&3)*16 + (j&15)
    int f = ((j >> 6) * 4 + ((j >> 4) & 3)) * 4 + (rb >> 2);
    int lane = (rb & 3) * 16 + (j & 15);
    unsigned base = (unsigned)(f * 64 + lane) * 6;
    #pragma unroll
    for (int d = 0; d < 6; ++d) EqB6[base + d] = dw[d];

    int sb = 127 + (int)e;
    SBtab[j * 16 + rb] = (unsigned char)(sb < 1 ? 1 : (sb > 254 ? 254 : sb));
}

__global__ __launch_bounds__(512, 2) void hmm_fwd(
    const int* __restrict__ obs,          // [B, T]
    const float* __restrict__ emis,       // [V, S]
    const float* __restrict__ prior,      // [S]
    const unsigned int* __restrict__ EqB6,// fp6 B lane fields, 6 dwords each
    const unsigned char* __restrict__ SBtab, // [512][16] e8m0 scale bytes
    float* __restrict__ out)              // [B]
{
    const int b = blockIdx.x;
    const int tid = threadIdx.x;          // state j owned by this thread
    const int lane = tid & 63, wv = tid >> 6;
    const int q = lane >> 4;              // 0..3
    const int hb = lane >> 5;             // 0..1

    __shared__ int obs_s[Tn];
    __shared__ __align__(16) unsigned int Pq6[2][96];  // packed fp6 P (384 B)
    __shared__ float redm[2][8];
    __shared__ float reds[8];

    obs_s[tid] = obs[b * Tn + tid];
    obs_s[tid + 512] = obs[b * Tn + 512 + tid];

    // B-fragments: Bf8[tau][kap] = cols wv*64+tau*16+(lane&15),
    // rows kap*128 + q*32 + [0,32), fp6-packed (6 live dwords of v8i)
    v8i Bf8[4][4];
    int SBv[4][4];
    #pragma unroll
    for (int tau = 0; tau < 4; ++tau) {
        int col = wv * 64 + tau * 16 + (lane & 15);
        #pragma unroll
        for (int kap = 0; kap < 4; ++kap) {
            const uint2* p = (const uint2*)(EqB6 +
                (unsigned)((((wv * 4 + tau) * 4 + kap) * 64 + lane) * 6));
            uint2 x0 = p[0], x1 = p[1], x2 = p[2];
            v8i bb = {(int)x0.x, (int)x0.y, (int)x1.x, (int)x1.y,
                      (int)x2.x, (int)x2.y, 0, 0};
            Bf8[tau][kap] = bb;
            SBv[tau][kap] = (int)SBtab[col * 16 + kap * 4 + q] * 0x01010101;
        }
    }

    __syncthreads();   // obs_s ready

    float a = emis[obs_s[0] * Sn + tid] + prior[tid];
    float e_next = emis[obs_s[1] * Sn + tid];

    for (int t = 1; t < Tn; ++t) {
        const int pb = t & 1;

        // ---- exact block max: DPP in-wave, b32 LDS round-trip cross-wave
        float mw = wave_max64(a);
        if (lane == 0) redm[pb][wv] = mw;
        __syncthreads();                          // barrier 1

        float r = redm[pb][lane & 7];
        float mAll = max_of_8_pattern(r);

        // per-64-chunk e8m0 exponents (pattern over lanes); cB = 1
        float nf = fmaxf(floorf((r - mAll) * L2E), -110.f);
        int sb = 126 + (int)nf;                   // sA = 127 + n - 1
        int sbdup = sb * 0x01010101;

        float nown = fmaxf(floorf((mw - mAll) * L2E), -110.f);

        // ---- quantize P to fp6 e2m3: v = 2^((a-mAll)*L2E + 1 - nown) in [0,4)
        float v = exp2f(fmaf(a - mAll, L2E, 1.0f - nown));
        int code = e2m3_rn(v);

        // quad merge -> 24-bit word (elements 4a..4a+3 in ascending 6-bit slots)
        int p1 = dpp_i<0xB1>(code);               // quad_perm [1,0,3,2]
        int m1 = (lane & 1) ? (p1 | (code << 6)) : (code | (p1 << 6));
        int p2 = dpp_i<0x4E>(m1);                 // quad_perm [2,3,0,1]
        int w24 = (lane & 2) ? (p2 | (m1 << 12)) : (m1 | (p2 << 12));

        // row assemble: 16 threads (4 quads) -> 96 bits -> 3 dwords
        int rowbase = lane & 48;
        int w1 = __shfl(w24, rowbase + 4, 64);
        int w2 = __shfl(w24, rowbase + 8, 64);
        int w3 = __shfl(w24, rowbase + 12, 64);
        int sel = lane & 15;
        unsigned dwv = sel == 0 ? (unsigned)(w24 | (w1 << 24))
                     : sel == 1 ? (unsigned)(((unsigned)w1 >> 8) | (w2 << 16))
                                : (unsigned)(((unsigned)w2 >> 16) | (w3 << 8));
        if (sel < 3) Pq6[pb][3 * (tid >> 4) + sel] = dwv;

        // A-scale dwords per kap (chunk w = 2*kap + hb) via readlane
        int ee0 = rl_i(sbdup, 0), ee1 = rl_i(sbdup, 1);
        int ee2 = rl_i(sbdup, 2), ee3 = rl_i(sbdup, 3);
        int ee4 = rl_i(sbdup, 4), ee5 = rl_i(sbdup, 5);
        int ee6 = rl_i(sbdup, 6), ee7 = rl_i(sbdup, 7);
        int sA0 = hb ? ee1 : ee0;
        int sA1 = hb ? ee3 : ee2;
        int sA2 = hb ? ee5 : ee4;
        int sA3 = hb ? ee7 : ee6;
        __syncthreads();                          // barrier 2

        float e_cur = e_next;
        if (t < Tn - 1) e_next = emis[obs_s[t + 1] * Sn + tid];

        // ---- A-fragments: quad-broadcast packed-P reads (all A-rows identical)
        // lane's field: k = kap*128 + q*32 .. +32 -> dwords kap*24 + q*6 .. +6
        v8i Af8[4];
        #pragma unroll
        for (int kap = 0; kap < 4; ++kap) {
            const uint2* pp = (const uint2*)(Pq6[pb] + kap * 24 + q * 6);
            uint2 x0 = pp[0], x1 = pp[1], x2 = pp[2];
            v8i aa = {(int)x0.x, (int)x0.y, (int)x1.x, (int)x1.y,
                      (int)x2.x, (int)x2.y, 0, 0};
            Af8[kap] = aa;
        }

        // ---- 4 tau x 4 kap scale-MFMAs (fp6 x fp6, K=128 each)
        float accx[4];
        #pragma unroll
        for (int tau = 0; tau < 4; ++tau) {
            v4f z = {0.f, 0.f, 0.f, 0.f};
            #pragma unroll
            for (int kap = 0; kap < 4; ++kap) {
                int sA = (kap == 0) ? sA0 : (kap == 1) ? sA1
                         : (kap == 2) ? sA2 : sA3;
                z = __builtin_amdgcn_mfma_scale_f32_16x16x128_f8f6f4(
                        Af8[kap], Bf8[tau][kap], z, 2, 2, 0, sA, 0, SBv[tau][kap]);
            }
            accx[tau] = z.x;
        }

        // ---- every C row equals the result: select tau = q in-register
        float fs = (lane < 16) ? accx[0]
                 : (lane < 32) ? accx[1]
                 : (lane < 48) ? accx[2]
                               : accx[3];

        a = e_cur + mAll + __logf(fs);
    }

    // ---- out[b] = logsumexp_j(alpha[j])
    float m = a;
    #pragma unroll
    for (int off = 32; off; off >>= 1) m = fmaxf(m, __shfl_xor(m, off, 64));
    if (lane == 0) redm[0][wv] = m;
    __syncthreads();
    #pragma unroll
    for (int w = 0; w < 8; ++w) m = fmaxf(m, redm[0][w]);

    float s = __expf(a - m);
    #pragma unroll
    for (int off = 32; off; off >>= 1) s += __shfl_xor(s, off, 64);
    if (lane == 0) reds[wv] = s;
    __syncthreads();
    if (tid == 0) {
        float tot = 0.f;
        #pragma unroll
        for (int w = 0; w < 8; ++w) tot += reds[w];
        out[b] = m + __logf(tot);
    }
}

extern "C" void kernel_launch(void* const* d_in, const int* in_sizes, int n_in,
                              void* d_out, int out_size, void* d_ws, size_t ws_size,
                              hipStream_t stream) {
    const int*   obs   = (const int*)d_in[0];
    const float* emis  = (const float*)d_in[1];
    const float* trans = (const float*)d_in[2];
    const float* prior = (const float*)d_in[3];
    float* out = (float*)d_out;

    unsigned int* EqB6 = (unsigned int*)d_ws;                  // 192 KB (fp6)
    unsigned char* SBtab = (unsigned char*)d_ws + Sn * Sn * 6 / 8; // 8 KB

    prep_E6<<<Sn / 4, 64, 0, stream>>>(trans, EqB6, SBtab);
    hmm_fwd<<<Bn, Sn, 0, stream>>>(obs, emis, prior, EqB6, SBtab, out);
}